// Round 1
// baseline (183.690 us; speedup 1.0000x reference)
//
#include <hip/hip_runtime.h>

// Problem constants
#define BS_   8192
#define HID   2048
#define DFF   5461
#define NE    8

// chunking
#define TP_NCH 128   // token chunks for t = dispatch^T x  (64 rows each)
#define TP_ROWS 64
#define MP_NH  16    // h-chunks (128 each) for up projection
#define MP_HC  128
#define EP_NFC 43    // f-chunks (128 each) for down projection
#define EP_FC  128

// ws (float offsets) -- small finals, ~576 KB total
#define WS_SPART 0        // 128 blocks x 16 floats (partial softmax stats)
#define WS_STATS 2048     // m[8], s[8]
#define WS_DISP  2112     // 65536 dispatch probs
#define WS_T     67648    // 8x2048
#define WS_MID   84032    // 8x5461
#define WS_EO    127720   // 8x2048

// d_out used as large scratch (float offsets); fully overwritten by k_comb
#define SC_TP 0           // 128*8*2048
#define SC_MP 2097152     // 16*8*5461
#define SC_EP 2796160     // 43*8*2048

__device__ __forceinline__ void merge_ms(float& m, float& s, float mo, float so) {
  float mn = fmaxf(m, mo);
  s = s * __expf(m - mn) + so * __expf(mo - mn);
  m = mn;
}

// ---- softmax stats over tokens (per expert), stage 1: 128 blocks x 64 threads
__global__ __launch_bounds__(64) void k_stats1(const float* __restrict__ rw,
                                               float* __restrict__ ws) {
  int b = blockIdx.x * 64 + threadIdx.x;
  const float4* r4 = (const float4*)(rw + (size_t)b * NE);
  float4 a = r4[0], c = r4[1];
  float m[NE] = {a.x, a.y, a.z, a.w, c.x, c.y, c.z, c.w};
  float s[NE];
#pragma unroll
  for (int e = 0; e < NE; e++) s[e] = 1.f;
#pragma unroll
  for (int off = 32; off >= 1; off >>= 1) {
#pragma unroll
    for (int e = 0; e < NE; e++) {
      float mo = __shfl_xor(m[e], off, 64);
      float so = __shfl_xor(s[e], off, 64);
      merge_ms(m[e], s[e], mo, so);
    }
  }
  if (threadIdx.x == 0) {
#pragma unroll
    for (int e = 0; e < NE; e++) {
      ws[WS_SPART + blockIdx.x * 16 + e] = m[e];
      ws[WS_SPART + blockIdx.x * 16 + 8 + e] = s[e];
    }
  }
}

// ---- softmax stats stage 2: merge 128 partials
__global__ __launch_bounds__(64) void k_stats2(float* __restrict__ ws) {
  int e = threadIdx.x;
  if (e < NE) {
    float m = -3.0e38f, s = 0.f;
    for (int b = 0; b < 128; b++)
      merge_ms(m, s, ws[WS_SPART + b * 16 + e], ws[WS_SPART + b * 16 + 8 + e]);
    ws[WS_STATS + e] = m;
    ws[WS_STATS + 8 + e] = s;
  }
}

// ---- dispatch[b,e] = exp(rw - m_e)/s_e
__global__ __launch_bounds__(256) void k_disp(const float* __restrict__ rw,
                                              float* __restrict__ ws) {
  int i = blockIdx.x * 256 + threadIdx.x;  // 65536 total
  int e = i & 7;
  float m = ws[WS_STATS + e], s = ws[WS_STATS + 8 + e];
  ws[WS_DISP + i] = __expf(rw[i] - m) / s;
}

// ---- t partials: t[e,h] over 64-token chunks. grid (2,128), block 256
__global__ __launch_bounds__(256) void k_tpart(const float* __restrict__ x,
                                               const float* __restrict__ ws,
                                               float* __restrict__ sc) {
  int c4 = blockIdx.x * 256 + threadIdx.x;  // float4 column 0..511
  int rc = blockIdx.y;
  float4 acc[NE];
#pragma unroll
  for (int e = 0; e < NE; e++) acc[e] = make_float4(0.f, 0.f, 0.f, 0.f);
  int b0 = rc * TP_ROWS;
  const float* dsp = ws + WS_DISP;
  for (int r = 0; r < TP_ROWS; r++) {
    int b = b0 + r;
    float4 xv = ((const float4*)(x + (size_t)b * HID))[c4];
    float4 d0 = ((const float4*)(dsp + (size_t)b * NE))[0];
    float4 d1 = ((const float4*)(dsp + (size_t)b * NE))[1];
    float dv[NE] = {d0.x, d0.y, d0.z, d0.w, d1.x, d1.y, d1.z, d1.w};
#pragma unroll
    for (int e = 0; e < NE; e++) {
      acc[e].x += dv[e] * xv.x;
      acc[e].y += dv[e] * xv.y;
      acc[e].z += dv[e] * xv.z;
      acc[e].w += dv[e] * xv.w;
    }
  }
#pragma unroll
  for (int e = 0; e < NE; e++)
    ((float4*)(sc + SC_TP + (size_t)(rc * NE + e) * HID))[c4] = acc[e];
}

// ---- t reduce: sum 128 chunks
__global__ __launch_bounds__(256) void k_tred(const float* __restrict__ sc,
                                              float* __restrict__ ws) {
  int i = blockIdx.x * 256 + threadIdx.x;  // 16384
  float a = 0.f;
  for (int rc = 0; rc < TP_NCH; rc++) a += sc[SC_TP + (size_t)rc * NE * HID + i];
  ws[WS_T + i] = a;
}

// ---- up-proj partials: grid (22 fblocks, 16 hchunks, 4 groups), block 256
__global__ __launch_bounds__(256) void k_midpart(const float* __restrict__ up_w,
                                                 const float* __restrict__ ws,
                                                 float* __restrict__ sc) {
  int fb = blockIdx.x, hc = blockIdx.y, g = blockIdx.z;
  int f = fb * 256 + threadIdx.x;
  __shared__ float t0[MP_HC], t1[MP_HC];
  int h0 = hc * MP_HC;
  if (threadIdx.x < MP_HC)
    t0[threadIdx.x] = ws[WS_T + (2 * g) * HID + h0 + threadIdx.x];
  else
    t1[threadIdx.x - MP_HC] = ws[WS_T + (2 * g + 1) * HID + h0 + threadIdx.x - MP_HC];
  __syncthreads();
  if (f >= DFF) return;
  const float* wp = up_w + ((size_t)g * HID + h0) * DFF + f;
  float a0 = 0.f, a1 = 0.f;
#pragma unroll 4
  for (int h = 0; h < MP_HC; h++) {
    float w = wp[(size_t)h * DFF];
    a0 += t0[h] * w;
    a1 += t1[h] * w;
  }
  sc[SC_MP + (size_t)(hc * NE + 2 * g) * DFF + f] = a0;
  sc[SC_MP + (size_t)(hc * NE + 2 * g + 1) * DFF + f] = a1;
}

// ---- mid reduce + bias + silu
__global__ __launch_bounds__(256) void k_midred(const float* __restrict__ sc,
                                                const float* __restrict__ up_b,
                                                float* __restrict__ ws) {
  int i = blockIdx.x * 256 + threadIdx.x;  // 8*5461 = 43688
  if (i >= NE * DFF) return;
  int e = i / DFF;
  int f = i - e * DFF;
  float a = up_b[(e >> 1) * DFF + f];
  for (int hc = 0; hc < MP_NH; hc++) a += sc[SC_MP + (size_t)hc * NE * DFF + i];
  ws[WS_MID + i] = a / (1.f + __expf(-a));  // silu
}

// ---- down-proj partials: grid (2 hblocks, 43 fchunks, 8 experts), block 256
__global__ __launch_bounds__(256) void k_eopart(const float* __restrict__ down_w,
                                                const float* __restrict__ ws,
                                                float* __restrict__ sc) {
  int hb = blockIdx.x, fc = blockIdx.y, e = blockIdx.z;
  int c4 = hb * 256 + threadIdx.x;  // float4 column 0..511
  __shared__ float ml[EP_FC];
  int f0 = fc * EP_FC;
  if (threadIdx.x < EP_FC) {
    int f = f0 + threadIdx.x;
    ml[threadIdx.x] = (f < DFF) ? ws[WS_MID + e * DFF + f] : 0.f;
  }
  __syncthreads();
  int nf = min(EP_FC, DFF - f0);
  const float* base = down_w + ((size_t)e * DFF + f0) * HID;
  float4 a = make_float4(0.f, 0.f, 0.f, 0.f);
  for (int f = 0; f < nf; f++) {
    float4 w = ((const float4*)(base + (size_t)f * HID))[c4];
    float mm = ml[f];
    a.x += mm * w.x;
    a.y += mm * w.y;
    a.z += mm * w.z;
    a.w += mm * w.w;
  }
  ((float4*)(sc + SC_EP + (size_t)(fc * NE + e) * HID))[c4] = a;
}

// ---- eo reduce + bias
__global__ __launch_bounds__(256) void k_eored(const float* __restrict__ sc,
                                               const float* __restrict__ down_b,
                                               float* __restrict__ ws) {
  int i = blockIdx.x * 256 + threadIdx.x;  // 16384
  float a = down_b[i];
  for (int fc = 0; fc < EP_NFC; fc++) a += sc[SC_EP + (size_t)fc * NE * HID + i];
  ws[WS_EO + i] = a;
}

// ---- combine: y[b,h] = sum_e disp[b,e] * eo[e,h]. grid 8192, block 256
__global__ __launch_bounds__(256) void k_comb(const float* __restrict__ ws,
                                              float* __restrict__ y) {
  int b = blockIdx.x;
  const float4* dp = (const float4*)(ws + WS_DISP + (size_t)b * NE);
  float4 d0 = dp[0], d1 = dp[1];
  float dv[NE] = {d0.x, d0.y, d0.z, d0.w, d1.x, d1.y, d1.z, d1.w};
  float4 o0 = make_float4(0.f, 0.f, 0.f, 0.f);
  float4 o1 = make_float4(0.f, 0.f, 0.f, 0.f);
#pragma unroll
  for (int e = 0; e < NE; e++) {
    const float4* eo = (const float4*)(ws + WS_EO + e * HID);
    float4 v0 = eo[threadIdx.x];
    float4 v1 = eo[threadIdx.x + 256];
    o0.x += dv[e] * v0.x;
    o0.y += dv[e] * v0.y;
    o0.z += dv[e] * v0.z;
    o0.w += dv[e] * v0.w;
    o1.x += dv[e] * v1.x;
    o1.y += dv[e] * v1.y;
    o1.z += dv[e] * v1.z;
    o1.w += dv[e] * v1.w;
  }
  ((float4*)(y + (size_t)b * HID))[threadIdx.x] = o0;
  ((float4*)(y + (size_t)b * HID))[threadIdx.x + 256] = o1;
}

extern "C" void kernel_launch(void* const* d_in, const int* in_sizes, int n_in,
                              void* d_out, int out_size, void* d_ws, size_t ws_size,
                              hipStream_t stream) {
  const float* x      = (const float*)d_in[0];
  const float* rw     = (const float*)d_in[1];
  const float* up_w   = (const float*)d_in[2];
  const float* up_b   = (const float*)d_in[3];
  const float* down_w = (const float*)d_in[4];
  const float* down_b = (const float*)d_in[5];
  float* y  = (float*)d_out;
  float* ws = (float*)d_ws;
  float* sc = y;  // large scratch lives in d_out; k_comb overwrites all of it

  hipLaunchKernelGGL(k_stats1, dim3(128), dim3(64), 0, stream, rw, ws);
  hipLaunchKernelGGL(k_stats2, dim3(1), dim3(64), 0, stream, ws);
  hipLaunchKernelGGL(k_disp, dim3(256), dim3(256), 0, stream, rw, ws);
  hipLaunchKernelGGL(k_tpart, dim3(2, 128), dim3(256), 0, stream, x, ws, sc);
  hipLaunchKernelGGL(k_tred, dim3(64), dim3(256), 0, stream, sc, ws);
  hipLaunchKernelGGL(k_midpart, dim3(22, 16, 4), dim3(256), 0, stream, up_w, ws, sc);
  hipLaunchKernelGGL(k_midred, dim3(171), dim3(256), 0, stream, sc, up_b, ws);
  hipLaunchKernelGGL(k_eopart, dim3(2, 43, 8), dim3(256), 0, stream, down_w, ws, sc);
  hipLaunchKernelGGL(k_eored, dim3(64), dim3(256), 0, stream, sc, down_b, ws);
  hipLaunchKernelGGL(k_comb, dim3(8192), dim3(256), 0, stream, ws, y);
}

// Round 2
// 183.575 us; speedup vs baseline: 1.0006x; 1.0006x over previous
//
#include <hip/hip_runtime.h>

// Problem constants
#define BS_   8192
#define HID   2048
#define DFF   5461
#define NE    8

// chunking
#define TP_NCH 128   // token chunks for t = dispatch^T x  (64 rows each)
#define TP_ROWS 64
#define MP_NH  16    // h-chunks (128 each) for up projection
#define MP_HC  128
#define EP_NFC 86    // f-chunks (64 each) for down projection
#define EP_FC  64

// ws (float offsets)
#define WS_STATS 0        // m[8], inv_s[8]
#define WS_T     64       // 8x2048  (e*2048+h)
#define WS_EO    16448    // 8x2048

// d_out used as large scratch (float offsets); fully overwritten by k_comb
#define SC_TP 0           // 128*8*2048 = 2,097,152
#define SC_MP 2097152     // 16*8*5461  =   698,808
#define SC_EP 2796160     // 86*8*2048  = 1,409,024  (end 4,205,184 < 16,777,216)

__device__ __forceinline__ void merge_ms(float& m, float& s, float mo, float so) {
  float mn = fmaxf(m, mo);
  s = s * __expf(m - mn) + so * __expf(mo - mn);
  m = mn;
}

// ---- softmax stats over tokens: one block per expert, write m and 1/s
__global__ __launch_bounds__(256) void k_stats(const float* __restrict__ rw,
                                               float* __restrict__ ws) {
  int e = blockIdx.x;
  int tid = threadIdx.x;
  float m = -3.0e38f, s = 0.f;
#pragma unroll 4
  for (int r = 0; r < 32; r++) {
    float v = rw[(size_t)(r * 256 + tid) * NE + e];
    float mn = fmaxf(m, v);
    s = s * __expf(m - mn) + __expf(v - mn);
    m = mn;
  }
#pragma unroll
  for (int off = 32; off >= 1; off >>= 1) {
    float mo = __shfl_xor(m, off, 64);
    float so = __shfl_xor(s, off, 64);
    merge_ms(m, s, mo, so);
  }
  __shared__ float ml[4], sl[4];
  if ((tid & 63) == 0) { ml[tid >> 6] = m; sl[tid >> 6] = s; }
  __syncthreads();
  if (tid == 0) {
#pragma unroll
    for (int w = 1; w < 4; w++) merge_ms(m, s, ml[w], sl[w]);
    ws[WS_STATS + e] = m;
    ws[WS_STATS + 8 + e] = 1.f / s;
  }
}

// ---- t partials: t[e,h] over 64-token chunks; dispatch recomputed into LDS
__global__ __launch_bounds__(256) void k_tpart(const float* __restrict__ x,
                                               const float* __restrict__ rw,
                                               const float* __restrict__ ws,
                                               float* __restrict__ sc) {
  __shared__ float4 dv4[TP_ROWS][2];
  int tid = threadIdx.x;
  int rc = blockIdx.y;
  int b0 = rc * TP_ROWS;
  if (tid < 128) {
    int row = tid >> 1, half = tid & 1;
    float4 rv = *(const float4*)(rw + (size_t)(b0 + row) * NE + half * 4);
    int e0 = half * 4;
    float4 d;
    d.x = __expf(rv.x - ws[WS_STATS + e0 + 0]) * ws[WS_STATS + 8 + e0 + 0];
    d.y = __expf(rv.y - ws[WS_STATS + e0 + 1]) * ws[WS_STATS + 8 + e0 + 1];
    d.z = __expf(rv.z - ws[WS_STATS + e0 + 2]) * ws[WS_STATS + 8 + e0 + 2];
    d.w = __expf(rv.w - ws[WS_STATS + e0 + 3]) * ws[WS_STATS + 8 + e0 + 3];
    dv4[row][half] = d;
  }
  __syncthreads();
  int c4 = blockIdx.x * 256 + tid;
  float4 acc[NE];
#pragma unroll
  for (int e = 0; e < NE; e++) acc[e] = make_float4(0.f, 0.f, 0.f, 0.f);
  const float4* x4 = (const float4*)x;
#pragma unroll 2
  for (int r = 0; r < TP_ROWS; r++) {
    float4 xv = x4[(size_t)(b0 + r) * 512 + c4];
    float4 dlo = dv4[r][0], dhi = dv4[r][1];
    float dv[NE] = {dlo.x, dlo.y, dlo.z, dlo.w, dhi.x, dhi.y, dhi.z, dhi.w};
#pragma unroll
    for (int e = 0; e < NE; e++) {
      acc[e].x += dv[e] * xv.x;
      acc[e].y += dv[e] * xv.y;
      acc[e].z += dv[e] * xv.z;
      acc[e].w += dv[e] * xv.w;
    }
  }
#pragma unroll
  for (int e = 0; e < NE; e++)
    ((float4*)(sc + SC_TP + (size_t)(rc * NE + e) * HID))[c4] = acc[e];
}

// ---- t reduce: sum 128 chunks
__global__ __launch_bounds__(256) void k_tred(const float* __restrict__ sc,
                                              float* __restrict__ ws) {
  int i = blockIdx.x * 256 + threadIdx.x;  // 16384
  float a = 0.f;
#pragma unroll 8
  for (int rc = 0; rc < TP_NCH; rc++) a += sc[SC_TP + (size_t)rc * NE * HID + i];
  ws[WS_T + i] = a;
}

// ---- up-proj partials: grid (22 fblocks, 16 hchunks, 4 groups), block 256
__global__ __launch_bounds__(256) void k_midpart(const float* __restrict__ up_w,
                                                 const float* __restrict__ ws,
                                                 float* __restrict__ sc) {
  int fb = blockIdx.x, hc = blockIdx.y, g = blockIdx.z;
  int f = fb * 256 + threadIdx.x;
  __shared__ float t0[MP_HC], t1[MP_HC];
  int h0 = hc * MP_HC;
  if (threadIdx.x < MP_HC)
    t0[threadIdx.x] = ws[WS_T + (2 * g) * HID + h0 + threadIdx.x];
  else
    t1[threadIdx.x - MP_HC] = ws[WS_T + (2 * g + 1) * HID + h0 + threadIdx.x - MP_HC];
  __syncthreads();
  if (f >= DFF) return;
  const float* wp = up_w + ((size_t)g * HID + h0) * DFF + f;
  float a0 = 0.f, a1 = 0.f;
#pragma unroll 8
  for (int h = 0; h < MP_HC; h++) {
    float w = wp[(size_t)h * DFF];
    a0 += t0[h] * w;
    a1 += t1[h] * w;
  }
  sc[SC_MP + (size_t)(hc * NE + 2 * g) * DFF + f] = a0;
  sc[SC_MP + (size_t)(hc * NE + 2 * g + 1) * DFF + f] = a1;
}

// ---- down-proj partials (fused mid reduce + bias + silu in prologue):
// grid (2 hblocks, 86 fchunks, 8 experts), block 256
__global__ __launch_bounds__(256) void k_eopart(const float* __restrict__ down_w,
                                                const float* __restrict__ up_b,
                                                const float* __restrict__ sc_mp,
                                                float* __restrict__ sc) {
  int hb = blockIdx.x, fc = blockIdx.y, e = blockIdx.z;
  int c4 = hb * 256 + threadIdx.x;  // float4 column 0..511
  __shared__ float ml[EP_FC];
  int f0 = fc * EP_FC;
  if (threadIdx.x < EP_FC) {
    int f = f0 + threadIdx.x;
    float a = 0.f;
    if (f < DFF) {
      a = up_b[(size_t)(e >> 1) * DFF + f];
#pragma unroll 4
      for (int hc = 0; hc < MP_NH; hc++)
        a += sc_mp[SC_MP + (size_t)(hc * NE + e) * DFF + f];
      a = a / (1.f + __expf(-a));  // silu
    }
    ml[threadIdx.x] = a;
  }
  __syncthreads();
  int nf = min(EP_FC, DFF - f0);
  const float* base = down_w + ((size_t)e * DFF + f0) * HID;
  float4 a = make_float4(0.f, 0.f, 0.f, 0.f);
#pragma unroll 4
  for (int f = 0; f < nf; f++) {
    float4 w = ((const float4*)(base + (size_t)f * HID))[c4];
    float mm = ml[f];
    a.x += mm * w.x;
    a.y += mm * w.y;
    a.z += mm * w.z;
    a.w += mm * w.w;
  }
  ((float4*)(sc + SC_EP + (size_t)(fc * NE + e) * HID))[c4] = a;
}

// ---- eo reduce + bias
__global__ __launch_bounds__(256) void k_eored(const float* __restrict__ sc,
                                               const float* __restrict__ down_b,
                                               float* __restrict__ ws) {
  int i = blockIdx.x * 256 + threadIdx.x;  // 16384
  float a = down_b[i];
#pragma unroll 8
  for (int fc = 0; fc < EP_NFC; fc++) a += sc[SC_EP + (size_t)fc * NE * HID + i];
  ws[WS_EO + i] = a;
}

// ---- combine: y[b,h] = sum_e disp[b,e]*eo[e,h]; 4 tokens/block, eo in regs
__global__ __launch_bounds__(256) void k_comb(const float* __restrict__ rw,
                                              const float* __restrict__ ws,
                                              float* __restrict__ y) {
  int tid = threadIdx.x;
  int b0 = blockIdx.x * 4;
  __shared__ float dvl[4][NE];
  if (tid < 32) {
    int tok = tid >> 3, e = tid & 7;
    dvl[tok][e] = __expf(rw[(size_t)(b0 + tok) * NE + e] - ws[WS_STATS + e]) *
                  ws[WS_STATS + 8 + e];
  }
  __syncthreads();
  const float4* eo4 = (const float4*)(ws + WS_EO);
  float4 ea[NE], eb[NE];
#pragma unroll
  for (int e = 0; e < NE; e++) {
    ea[e] = eo4[e * 512 + tid];
    eb[e] = eo4[e * 512 + 256 + tid];
  }
  float4* y4 = (float4*)y;
#pragma unroll
  for (int t = 0; t < 4; t++) {
    float4 o0 = make_float4(0.f, 0.f, 0.f, 0.f);
    float4 o1 = make_float4(0.f, 0.f, 0.f, 0.f);
#pragma unroll
    for (int e = 0; e < NE; e++) {
      float d = dvl[t][e];
      o0.x += d * ea[e].x;
      o0.y += d * ea[e].y;
      o0.z += d * ea[e].z;
      o0.w += d * ea[e].w;
      o1.x += d * eb[e].x;
      o1.y += d * eb[e].y;
      o1.z += d * eb[e].z;
      o1.w += d * eb[e].w;
    }
    y4[(size_t)(b0 + t) * 512 + tid] = o0;
    y4[(size_t)(b0 + t) * 512 + 256 + tid] = o1;
  }
}

extern "C" void kernel_launch(void* const* d_in, const int* in_sizes, int n_in,
                              void* d_out, int out_size, void* d_ws, size_t ws_size,
                              hipStream_t stream) {
  const float* x      = (const float*)d_in[0];
  const float* rw     = (const float*)d_in[1];
  const float* up_w   = (const float*)d_in[2];
  const float* up_b   = (const float*)d_in[3];
  const float* down_w = (const float*)d_in[4];
  const float* down_b = (const float*)d_in[5];
  float* y  = (float*)d_out;
  float* ws = (float*)d_ws;
  float* sc = y;  // large scratch in d_out; k_comb overwrites all of it

  hipLaunchKernelGGL(k_stats, dim3(8), dim3(256), 0, stream, rw, ws);
  hipLaunchKernelGGL(k_tpart, dim3(2, 128), dim3(256), 0, stream, x, rw, ws, sc);
  hipLaunchKernelGGL(k_tred, dim3(64), dim3(256), 0, stream, sc, ws);
  hipLaunchKernelGGL(k_midpart, dim3(22, 16, 4), dim3(256), 0, stream, up_w, ws, sc);
  hipLaunchKernelGGL(k_eopart, dim3(2, 86, 8), dim3(256), 0, stream, down_w, up_b, sc, sc);
  hipLaunchKernelGGL(k_eored, dim3(64), dim3(256), 0, stream, sc, down_b, ws);
  hipLaunchKernelGGL(k_comb, dim3(2048), dim3(256), 0, stream, rw, ws, y);
}

// Round 3
// 173.748 us; speedup vs baseline: 1.0572x; 1.0566x over previous
//
#include <hip/hip_runtime.h>

#define HID   2048
#define DFF   5461
#define NE    8

// ws float offsets
#define WS_SPART 0        // 32 chunks * 8 experts * 2 = 512
#define WS_STATS 512      // m[8], inv_s[8]
#define WS_T     768      // 8*2048
#define WS_EO    17152    // 8*2048

// d_out used as large scratch (float offsets); fully overwritten by k_comb
#define SC_TP 0           // 128*8*2048 = 2,097,152
#define SC_MP 2097152     // 32*8*5461 = 1,398,016 -> end 3,495,168
#define SC_EP 3495168     // 171*8*2048 = 2,801,664 -> end 6,296,832 (< 16,777,216)

__device__ __forceinline__ void merge_ms(float& m, float& s, float mo, float so) {
  float mn = fmaxf(m, mo);
  s = s * __expf(m - mn) + so * __expf(mo - mn);
  m = mn;
}

// ---- softmax stats stage 1: 32 token-chunks x 8 experts = 256 blocks
__global__ __launch_bounds__(256) void k_stats1(const float* __restrict__ rw,
                                                float* __restrict__ ws) {
  int ch = blockIdx.x & 31, e = blockIdx.x >> 5;
  int tid = threadIdx.x;
  float m = rw[(size_t)(ch * 256 + tid) * NE + e];
  float s = 1.f;
#pragma unroll
  for (int off = 32; off >= 1; off >>= 1) {
    float mo = __shfl_xor(m, off, 64);
    float so = __shfl_xor(s, off, 64);
    merge_ms(m, s, mo, so);
  }
  __shared__ float ml[4], sl[4];
  if ((tid & 63) == 0) { ml[tid >> 6] = m; sl[tid >> 6] = s; }
  __syncthreads();
  if (tid == 0) {
#pragma unroll
    for (int w = 1; w < 4; w++) merge_ms(m, s, ml[w], sl[w]);
    ws[WS_SPART + (ch * NE + e) * 2] = m;
    ws[WS_SPART + (ch * NE + e) * 2 + 1] = s;
  }
}

// ---- softmax stats stage 2: merge 32 chunk-partials per expert
__global__ __launch_bounds__(64) void k_stats2(float* __restrict__ ws) {
  int e = threadIdx.x;
  if (e < NE) {
    float m = -3.0e38f, s = 0.f;
    for (int ch = 0; ch < 32; ch++)
      merge_ms(m, s, ws[WS_SPART + (ch * NE + e) * 2],
               ws[WS_SPART + (ch * NE + e) * 2 + 1]);
    ws[WS_STATS + e] = m;
    ws[WS_STATS + 8 + e] = 1.f / s;
  }
}

// ---- t partials: grid (4 col-blocks, 128 row-chunks), block 256
__global__ __launch_bounds__(256) void k_tpart(const float* __restrict__ x,
                                               const float* __restrict__ rw,
                                               const float* __restrict__ ws,
                                               float* __restrict__ sc) {
  __shared__ float4 dv4[64][2];
  __shared__ float4 red[NE][128];
  int tid = threadIdx.x;
  int rc = blockIdx.y, b0 = rc * 64;
  if (tid < 128) {
    int row = tid >> 1, half = tid & 1;
    float4 rv = *(const float4*)(rw + (size_t)(b0 + row) * NE + half * 4);
    int e0 = half * 4;
    float4 d;
    d.x = __expf(rv.x - ws[WS_STATS + e0 + 0]) * ws[WS_STATS + 8 + e0 + 0];
    d.y = __expf(rv.y - ws[WS_STATS + e0 + 1]) * ws[WS_STATS + 8 + e0 + 1];
    d.z = __expf(rv.z - ws[WS_STATS + e0 + 2]) * ws[WS_STATS + 8 + e0 + 2];
    d.w = __expf(rv.w - ws[WS_STATS + e0 + 3]) * ws[WS_STATS + 8 + e0 + 3];
    dv4[row][half] = d;
  }
  __syncthreads();
  int col = tid & 127, rg = tid >> 7;
  int c4 = blockIdx.x * 128 + col;
  float4 acc[NE];
#pragma unroll
  for (int e = 0; e < NE; e++) acc[e] = make_float4(0.f, 0.f, 0.f, 0.f);
  const float4* x4 = (const float4*)x;
#pragma unroll 4
  for (int r = 0; r < 32; r++) {
    int row = rg * 32 + r;
    float4 xv = x4[(size_t)(b0 + row) * 512 + c4];
    float4 dlo = dv4[row][0], dhi = dv4[row][1];
    float dv[NE] = {dlo.x, dlo.y, dlo.z, dlo.w, dhi.x, dhi.y, dhi.z, dhi.w};
#pragma unroll
    for (int e = 0; e < NE; e++) {
      acc[e].x += dv[e] * xv.x;
      acc[e].y += dv[e] * xv.y;
      acc[e].z += dv[e] * xv.z;
      acc[e].w += dv[e] * xv.w;
    }
  }
  if (rg == 1) {
#pragma unroll
    for (int e = 0; e < NE; e++) red[e][col] = acc[e];
  }
  __syncthreads();
  if (rg == 0) {
    float4* o4 = (float4*)(sc + SC_TP);
#pragma unroll
    for (int e = 0; e < NE; e++) {
      float4 r2 = red[e][col];
      acc[e].x += r2.x; acc[e].y += r2.y; acc[e].z += r2.z; acc[e].w += r2.w;
      o4[(size_t)(rc * NE + e) * 512 + blockIdx.x * 128 + col] = acc[e];
    }
  }
}

// ---- t reduce: 512 blocks, 32 outputs each, 8 chunk-groups
__global__ __launch_bounds__(256) void k_tred(const float* __restrict__ sc,
                                              float* __restrict__ ws) {
  __shared__ float red[8][32];
  int tid = threadIdx.x;
  int o = tid & 31, grp = tid >> 5;
  int i = blockIdx.x * 32 + o;
  float a = 0.f;
#pragma unroll 4
  for (int k = 0; k < 16; k++)
    a += sc[SC_TP + (size_t)(grp * 16 + k) * (NE * HID) + i];
  red[grp][o] = a;
  __syncthreads();
  if (tid < 32) {
    float s = 0.f;
#pragma unroll
    for (int g = 0; g < 8; g++) s += red[g][tid];
    ws[WS_T + blockIdx.x * 32 + tid] = s;
  }
}

// ---- up-proj partials: grid (11 f-spans of 512, 32 h-chunks of 64, 4 groups)
__global__ __launch_bounds__(256) void k_midpart(const float* __restrict__ up_w,
                                                 const float* __restrict__ ws,
                                                 float* __restrict__ sc) {
  int fb = blockIdx.x, hc = blockIdx.y, g = blockIdx.z;
  int tid = threadIdx.x;
  __shared__ float t0[64], t1[64];
  int h0 = hc * 64;
  if (tid < 64) t0[tid] = ws[WS_T + (2 * g) * HID + h0 + tid];
  else if (tid < 128) t1[tid - 64] = ws[WS_T + (2 * g + 1) * HID + h0 + tid - 64];
  __syncthreads();
  int fA = fb * 512 + tid;       // always < DFF (max 5375)
  int fB = fA + 256;
  bool hasB = fB < DFF;
  const float* wp = up_w + ((size_t)g * HID + h0) * DFF;
  float a0 = 0.f, a1 = 0.f, bb0 = 0.f, bb1 = 0.f;
#pragma unroll 4
  for (int h = 0; h < 64; h++) {
    float wA = wp[(size_t)h * DFF + fA];
    float wB = hasB ? wp[(size_t)h * DFF + fB] : 0.f;
    a0 += t0[h] * wA;
    a1 += t1[h] * wA;
    bb0 += t0[h] * wB;
    bb1 += t1[h] * wB;
  }
  float* mp = sc + SC_MP + (size_t)hc * NE * DFF;
  mp[(size_t)(2 * g) * DFF + fA] = a0;
  mp[(size_t)(2 * g + 1) * DFF + fA] = a1;
  if (hasB) {
    mp[(size_t)(2 * g) * DFF + fB] = bb0;
    mp[(size_t)(2 * g + 1) * DFF + fB] = bb1;
  }
}

// ---- down-proj partials (fused mid reduce + bias + silu):
// grid (2 h-halves, 171 f-chunks of 32, 8 experts)
__global__ __launch_bounds__(256) void k_eopart(const float* __restrict__ down_w,
                                                const float* __restrict__ up_b,
                                                const float* __restrict__ sc_mp,
                                                float* __restrict__ sc) {
  int hb = blockIdx.x, fc = blockIdx.y, e = blockIdx.z;
  int tid = threadIdx.x;
  int f0 = fc * 32;
  __shared__ float red[8][32];
  __shared__ float ml[32];
  {
    int fl = tid & 31, grp = tid >> 5;
    int f = f0 + fl;
    float a = 0.f;
    if (f < DFF) {
#pragma unroll
      for (int k = 0; k < 4; k++)
        a += sc_mp[SC_MP + ((size_t)(grp * 4 + k) * NE + e) * DFF + f];
    }
    red[grp][fl] = a;
  }
  __syncthreads();
  if (tid < 32) {
    int f = f0 + tid;
    float a = 0.f;
    if (f < DFF) {
      a = up_b[(size_t)(e >> 1) * DFF + f];
#pragma unroll
      for (int g = 0; g < 8; g++) a += red[g][tid];
      a = a / (1.f + __expf(-a));  // silu
    }
    ml[tid] = a;
  }
  __syncthreads();
  int nf = min(32, DFF - f0);
  const float4* base = (const float4*)(down_w + ((size_t)e * DFF + f0) * HID + hb * 1024);
  float4 acc = make_float4(0.f, 0.f, 0.f, 0.f);
#pragma unroll 8
  for (int fi = 0; fi < nf; fi++) {
    float4 w = base[(size_t)fi * 512 + tid];
    float mm = ml[fi];
    acc.x += mm * w.x;
    acc.y += mm * w.y;
    acc.z += mm * w.z;
    acc.w += mm * w.w;
  }
  ((float4*)(sc + SC_EP))[(size_t)(fc * NE + e) * 512 + hb * 256 + tid] = acc;
}

// ---- eo reduce + bias: 512 blocks, 32 outputs each
__global__ __launch_bounds__(256) void k_eored(const float* __restrict__ sc,
                                               const float* __restrict__ down_b,
                                               float* __restrict__ ws) {
  __shared__ float red[8][32];
  int tid = threadIdx.x;
  int o = tid & 31, grp = tid >> 5;
  int i = blockIdx.x * 32 + o;
  float a = 0.f;
  for (int fc = grp; fc < 171; fc += 8)
    a += sc[SC_EP + (size_t)fc * (NE * HID) + i];
  red[grp][o] = a;
  __syncthreads();
  if (tid < 32) {
    int ii = blockIdx.x * 32 + tid;
    float s = down_b[ii];
#pragma unroll
    for (int g = 0; g < 8; g++) s += red[g][tid];
    ws[WS_EO + ii] = s;
  }
}

// ---- combine: y[b,h] = sum_e disp[b,e]*eo[e,h]; 4 tokens/block, eo in regs
__global__ __launch_bounds__(256) void k_comb(const float* __restrict__ rw,
                                              const float* __restrict__ ws,
                                              float* __restrict__ y) {
  int tid = threadIdx.x;
  int b0 = blockIdx.x * 4;
  __shared__ float dvl[4][NE];
  if (tid < 32) {
    int tok = tid >> 3, e = tid & 7;
    dvl[tok][e] = __expf(rw[(size_t)(b0 + tok) * NE + e] - ws[WS_STATS + e]) *
                  ws[WS_STATS + 8 + e];
  }
  __syncthreads();
  const float4* eo4 = (const float4*)(ws + WS_EO);
  float4 ea[NE], eb[NE];
#pragma unroll
  for (int e = 0; e < NE; e++) {
    ea[e] = eo4[e * 512 + tid];
    eb[e] = eo4[e * 512 + 256 + tid];
  }
  float4* y4 = (float4*)y;
#pragma unroll
  for (int t = 0; t < 4; t++) {
    float4 o0 = make_float4(0.f, 0.f, 0.f, 0.f);
    float4 o1 = make_float4(0.f, 0.f, 0.f, 0.f);
#pragma unroll
    for (int e = 0; e < NE; e++) {
      float d = dvl[t][e];
      o0.x += d * ea[e].x;
      o0.y += d * ea[e].y;
      o0.z += d * ea[e].z;
      o0.w += d * ea[e].w;
      o1.x += d * eb[e].x;
      o1.y += d * eb[e].y;
      o1.z += d * eb[e].z;
      o1.w += d * eb[e].w;
    }
    y4[(size_t)(b0 + t) * 512 + tid] = o0;
    y4[(size_t)(b0 + t) * 512 + 256 + tid] = o1;
  }
}

extern "C" void kernel_launch(void* const* d_in, const int* in_sizes, int n_in,
                              void* d_out, int out_size, void* d_ws, size_t ws_size,
                              hipStream_t stream) {
  const float* x      = (const float*)d_in[0];
  const float* rw     = (const float*)d_in[1];
  const float* up_w   = (const float*)d_in[2];
  const float* up_b   = (const float*)d_in[3];
  const float* down_w = (const float*)d_in[4];
  const float* down_b = (const float*)d_in[5];
  float* y  = (float*)d_out;
  float* ws = (float*)d_ws;
  float* sc = y;  // large scratch in d_out; k_comb overwrites all of it

  hipLaunchKernelGGL(k_stats1, dim3(256), dim3(256), 0, stream, rw, ws);
  hipLaunchKernelGGL(k_stats2, dim3(1), dim3(64), 0, stream, ws);
  hipLaunchKernelGGL(k_tpart, dim3(4, 128), dim3(256), 0, stream, x, rw, ws, sc);
  hipLaunchKernelGGL(k_tred, dim3(512), dim3(256), 0, stream, sc, ws);
  hipLaunchKernelGGL(k_midpart, dim3(11, 32, 4), dim3(256), 0, stream, up_w, ws, sc);
  hipLaunchKernelGGL(k_eopart, dim3(2, 171, 8), dim3(256), 0, stream, down_w, up_b, sc, sc);
  hipLaunchKernelGGL(k_eored, dim3(512), dim3(256), 0, stream, sc, down_b, ws);
  hipLaunchKernelGGL(k_comb, dim3(2048), dim3(256), 0, stream, rw, ws, y);
}

// Round 4
// 143.303 us; speedup vs baseline: 1.2818x; 1.2125x over previous
//
#include <hip/hip_runtime.h>

typedef float f4 __attribute__((ext_vector_type(4)));

#define HID 2048
#define DFF 5461
#define NE  8

// ws float offsets
#define WS_STATS 0        // m[8], inv_s[8]
#define WS_T     64       // 8*2048
#define WS_EO    16448    // 8*2048

// d_out used as large scratch (float offsets); fully overwritten by k_comb
#define SC_TP 0           // 256*8*2048 = 4,194,304
#define SC_MP 4194304     // 32*8*5461  = 1,398,016 -> end 5,592,320
#define SC_EP 5592320     // 127*8*2048 = 2,080,768 -> end 7,673,088 (< 16,777,216)

__device__ __forceinline__ void merge_ms(float& m, float& s, float mo, float so) {
  float mn = fmaxf(m, mo);
  s = s * __expf(m - mn) + so * __expf(mo - mn);
  m = mn;
}

// ---- softmax stats over tokens: one block per expert
__global__ __launch_bounds__(256) void k_stats(const float* __restrict__ rw,
                                               float* __restrict__ ws) {
  int e = blockIdx.x, tid = threadIdx.x;
  float m = -3.0e38f, s = 0.f;
#pragma unroll 4
  for (int r = 0; r < 32; r++) {
    float v = rw[(size_t)(r * 256 + tid) * NE + e];
    float mn = fmaxf(m, v);
    s = s * __expf(m - mn) + __expf(v - mn);
    m = mn;
  }
#pragma unroll
  for (int off = 32; off >= 1; off >>= 1) {
    float mo = __shfl_xor(m, off, 64);
    float so = __shfl_xor(s, off, 64);
    merge_ms(m, s, mo, so);
  }
  __shared__ float ml[4], sl[4];
  if ((tid & 63) == 0) { ml[tid >> 6] = m; sl[tid >> 6] = s; }
  __syncthreads();
  if (tid == 0) {
#pragma unroll
    for (int w = 1; w < 4; w++) merge_ms(m, s, ml[w], sl[w]);
    ws[WS_STATS + e] = m;
    ws[WS_STATS + 8 + e] = 1.f / s;
  }
}

// ---- t partials: grid (4 col-blocks, 256 row-chunks of 32), block 256
__global__ __launch_bounds__(256) void k_tpart(const float* __restrict__ x,
                                               const float* __restrict__ rw,
                                               const float* __restrict__ ws,
                                               float* __restrict__ sc) {
  __shared__ f4 dv4[32][2];
  __shared__ f4 red[NE][128];
  int tid = threadIdx.x;
  int rc = blockIdx.y, b0 = rc * 32;
  if (tid < 64) {
    int row = tid >> 1, half = tid & 1;
    const float* rp = rw + (size_t)(b0 + row) * NE + half * 4;
    int e0 = half * 4;
    f4 d;
    d.x = __expf(rp[0] - ws[WS_STATS + e0 + 0]) * ws[WS_STATS + 8 + e0 + 0];
    d.y = __expf(rp[1] - ws[WS_STATS + e0 + 1]) * ws[WS_STATS + 8 + e0 + 1];
    d.z = __expf(rp[2] - ws[WS_STATS + e0 + 2]) * ws[WS_STATS + 8 + e0 + 2];
    d.w = __expf(rp[3] - ws[WS_STATS + e0 + 3]) * ws[WS_STATS + 8 + e0 + 3];
    dv4[row][half] = d;
  }
  __syncthreads();
  int col = tid & 127, rg = tid >> 7;
  int c4 = blockIdx.x * 128 + col;
  f4 acc[NE];
#pragma unroll
  for (int e = 0; e < NE; e++) acc[e] = (f4){0.f, 0.f, 0.f, 0.f};
  const f4* x4 = (const f4*)x;
#pragma unroll 4
  for (int r = 0; r < 16; r++) {
    int row = rg * 16 + r;
    f4 xv = __builtin_nontemporal_load(&x4[(size_t)(b0 + row) * 512 + c4]);
    f4 dlo = dv4[row][0], dhi = dv4[row][1];
    acc[0] += dlo.x * xv;
    acc[1] += dlo.y * xv;
    acc[2] += dlo.z * xv;
    acc[3] += dlo.w * xv;
    acc[4] += dhi.x * xv;
    acc[5] += dhi.y * xv;
    acc[6] += dhi.z * xv;
    acc[7] += dhi.w * xv;
  }
  if (rg) {
#pragma unroll
    for (int e = 0; e < NE; e++) red[e][col] = acc[e];
  }
  __syncthreads();
  if (!rg) {
    f4* o4 = (f4*)(sc + SC_TP);
#pragma unroll
    for (int e = 0; e < NE; e++)
      o4[(size_t)(rc * NE + e) * 512 + c4] = acc[e] + red[e][col];
  }
}

// ---- t reduce: 512 blocks, 32 outputs each, 8 chunk-groups of 32
__global__ __launch_bounds__(256) void k_tred(const float* __restrict__ sc,
                                              float* __restrict__ ws) {
  __shared__ float red[8][32];
  int tid = threadIdx.x;
  int o = tid & 31, grp = tid >> 5;
  int i = blockIdx.x * 32 + o;
  float a = 0.f;
#pragma unroll 8
  for (int k = 0; k < 32; k++)
    a += sc[SC_TP + (size_t)(grp * 32 + k) * (NE * HID) + i];
  red[grp][o] = a;
  __syncthreads();
  if (tid < 32) {
    float s = 0.f;
#pragma unroll
    for (int g = 0; g < 8; g++) s += red[g][tid];
    ws[WS_T + blockIdx.x * 32 + tid] = s;
  }
}

// ---- up-proj partials: grid (11 f-spans of 512, 32 h-chunks of 64, 4 groups)
__global__ __launch_bounds__(256) void k_midpart(const float* __restrict__ up_w,
                                                 const float* __restrict__ ws,
                                                 float* __restrict__ sc) {
  int fb = blockIdx.x, hc = blockIdx.y, g = blockIdx.z;
  int tid = threadIdx.x;
  __shared__ float t0[64], t1[64];
  int h0 = hc * 64;
  if (tid < 64) t0[tid] = ws[WS_T + (2 * g) * HID + h0 + tid];
  else if (tid < 128) t1[tid - 64] = ws[WS_T + (2 * g + 1) * HID + h0 + tid - 64];
  __syncthreads();
  int fA = fb * 512 + tid;  // < 5376 always
  int fB = fA + 256;
  bool hasB = fB < DFF;
  const float* wp = up_w + ((size_t)g * HID + h0) * DFF;
  float a0 = 0.f, a1 = 0.f, bb0 = 0.f, bb1 = 0.f;
#pragma unroll 8
  for (int h = 0; h < 64; h++) {
    float wA = __builtin_nontemporal_load(wp + (size_t)h * DFF + fA);
    float wB = hasB ? __builtin_nontemporal_load(wp + (size_t)h * DFF + fB) : 0.f;
    a0 += t0[h] * wA;
    a1 += t1[h] * wA;
    bb0 += t0[h] * wB;
    bb1 += t1[h] * wB;
  }
  float* mp = sc + SC_MP + (size_t)hc * NE * DFF;
  mp[(size_t)(2 * g) * DFF + fA] = a0;
  mp[(size_t)(2 * g + 1) * DFF + fA] = a1;
  if (hasB) {
    mp[(size_t)(2 * g) * DFF + fB] = bb0;
    mp[(size_t)(2 * g + 1) * DFF + fB] = bb1;
  }
}

// ---- down-proj: grid (2 h-halves, 127 f-chunks of 43, 8 experts), block 256
// fused mid reduce + bias + silu (wave-local, no barrier); 8-row preload pipeline
__global__ __launch_bounds__(256) void k_eopart(const float* __restrict__ down_w,
                                                const float* __restrict__ up_b,
                                                const float* __restrict__ sc_mp,
                                                float* __restrict__ sc) {
  int hb = blockIdx.x, fc = blockIdx.y, e = blockIdx.z;
  int tid = threadIdx.x;
  int f0 = fc * 43;
  const f4* base4 = (const f4*)down_w + ((size_t)e * DFF + f0) * 512 + hb * 256 + tid;
  // preload first 8 rows (in flight across the prologue)
  f4 w[8];
#pragma unroll
  for (int j = 0; j < 8; j++)
    w[j] = __builtin_nontemporal_load(&base4[(size_t)j * 512]);
  // wave-local mid finalize: 32-chunk reduce + bias + silu (no __syncthreads)
  __shared__ float ml[4][43];
  int lane = tid & 63, wv = tid >> 6;
  if (lane < 43) {
    float a = up_b[(size_t)(e >> 1) * DFF + f0 + lane];
#pragma unroll 8
    for (int k = 0; k < 32; k++)
      a += sc_mp[SC_MP + (size_t)(k * NE + e) * DFF + f0 + lane];
    ml[wv][lane] = a / (1.f + __expf(-a));
  }
  f4 acc = (f4){0.f, 0.f, 0.f, 0.f};
  for (int blk = 0; blk < 5; blk++) {
#pragma unroll
    for (int j = 0; j < 8; j++) {
      int cur = blk * 8 + j;
      f4 c = w[j];
      int nxt = cur + 8;
      if (nxt < 43) w[j] = __builtin_nontemporal_load(&base4[(size_t)nxt * 512]);
      acc += ml[wv][cur] * c;
    }
  }
#pragma unroll
  for (int j = 0; j < 3; j++) acc += ml[wv][40 + j] * w[j];
  ((f4*)(sc + SC_EP))[(size_t)(fc * NE + e) * 512 + hb * 256 + tid] = acc;
}

// ---- eo reduce + bias: 512 blocks, 32 outputs each
__global__ __launch_bounds__(256) void k_eored(const float* __restrict__ sc,
                                               const float* __restrict__ down_b,
                                               float* __restrict__ ws) {
  __shared__ float red[8][32];
  int tid = threadIdx.x;
  int o = tid & 31, grp = tid >> 5;
  int i = blockIdx.x * 32 + o;
  float a = 0.f;
  for (int fc = grp; fc < 127; fc += 8)
    a += sc[SC_EP + (size_t)fc * (NE * HID) + i];
  red[grp][o] = a;
  __syncthreads();
  if (tid < 32) {
    int ii = blockIdx.x * 32 + tid;
    float s = down_b[ii];
#pragma unroll
    for (int g = 0; g < 8; g++) s += red[g][tid];
    ws[WS_EO + ii] = s;
  }
}

// ---- combine: 16 tokens/block, eo in regs, nt stores
__global__ __launch_bounds__(256) void k_comb(const float* __restrict__ rw,
                                              const float* __restrict__ ws,
                                              float* __restrict__ y) {
  int tid = threadIdx.x;
  int b0 = blockIdx.x * 16;
  __shared__ float dvl[16][NE];
  if (tid < 128) {
    int tok = tid >> 3, e = tid & 7;
    dvl[tok][e] = __expf(rw[(size_t)(b0 + tok) * NE + e] - ws[WS_STATS + e]) *
                  ws[WS_STATS + 8 + e];
  }
  __syncthreads();
  const f4* eo4 = (const f4*)(ws + WS_EO);
  f4 ea[NE], eb[NE];
#pragma unroll
  for (int e = 0; e < NE; e++) {
    ea[e] = eo4[e * 512 + tid];
    eb[e] = eo4[e * 512 + 256 + tid];
  }
  f4* y4 = (f4*)y;
#pragma unroll 4
  for (int t = 0; t < 16; t++) {
    f4 o0 = (f4){0.f, 0.f, 0.f, 0.f};
    f4 o1 = (f4){0.f, 0.f, 0.f, 0.f};
#pragma unroll
    for (int e = 0; e < NE; e++) {
      float d = dvl[t][e];
      o0 += d * ea[e];
      o1 += d * eb[e];
    }
    __builtin_nontemporal_store(o0, &y4[(size_t)(b0 + t) * 512 + tid]);
    __builtin_nontemporal_store(o1, &y4[(size_t)(b0 + t) * 512 + 256 + tid]);
  }
}

extern "C" void kernel_launch(void* const* d_in, const int* in_sizes, int n_in,
                              void* d_out, int out_size, void* d_ws, size_t ws_size,
                              hipStream_t stream) {
  const float* x      = (const float*)d_in[0];
  const float* rw     = (const float*)d_in[1];
  const float* up_w   = (const float*)d_in[2];
  const float* up_b   = (const float*)d_in[3];
  const float* down_w = (const float*)d_in[4];
  const float* down_b = (const float*)d_in[5];
  float* y  = (float*)d_out;
  float* ws = (float*)d_ws;
  float* sc = y;  // large scratch in d_out; k_comb overwrites all of it

  hipLaunchKernelGGL(k_stats, dim3(8), dim3(256), 0, stream, rw, ws);
  hipLaunchKernelGGL(k_tpart, dim3(4, 256), dim3(256), 0, stream, x, rw, ws, sc);
  hipLaunchKernelGGL(k_tred, dim3(512), dim3(256), 0, stream, sc, ws);
  hipLaunchKernelGGL(k_midpart, dim3(11, 32, 4), dim3(256), 0, stream, up_w, ws, sc);
  hipLaunchKernelGGL(k_eopart, dim3(2, 127, 8), dim3(256), 0, stream, down_w, up_b, sc, sc);
  hipLaunchKernelGGL(k_eored, dim3(512), dim3(256), 0, stream, sc, down_b, ws);
  hipLaunchKernelGGL(k_comb, dim3(512), dim3(256), 0, stream, rw, ws, y);
}

// Round 8
// 137.889 us; speedup vs baseline: 1.3322x; 1.0393x over previous
//
#include <hip/hip_runtime.h>

typedef float f4 __attribute__((ext_vector_type(4)));

#define HID 2048
#define DFF 5461
#define NE  8

// ws float offsets
#define WS_M  0           // m[8]
#define WS_IS 8           // inv_s[8]
#define WS_T  64          // 8*2048 (normalized t)
#define WS_EO 16448       // 8*2048

// d_out used as large scratch (float offsets); fully overwritten by k_comb
#define SC_TP 0           // 128 chunks * 8 e * 2048 h = 2,097,152
#define SC_MP 2097152     // 16*8*5461 = 699,008 -> end 2,796,160
#define SC_EP 2796288     // 127*8*2048 = 2,080,768 -> end 4,877,056 (< 16,777,216)

__device__ __forceinline__ void merge_ms(float& m, float& s, float mo, float so) {
  float mn = fmaxf(m, mo);
  s = s * __expf(m - mn) + so * __expf(mo - mn);
  m = mn;
}

// ---- softmax stats over tokens: one block per expert (R4-verified numerics)
__global__ __launch_bounds__(256) void k_stats(const float* __restrict__ rw,
                                               float* __restrict__ ws) {
  int e = blockIdx.x, tid = threadIdx.x;
  float m = -3.0e38f, s = 0.f;
#pragma unroll 4
  for (int r = 0; r < 32; r++) {
    float v = rw[(size_t)(r * 256 + tid) * NE + e];
    float mn = fmaxf(m, v);
    s = s * __expf(m - mn) + __expf(v - mn);
    m = mn;
  }
#pragma unroll
  for (int off = 32; off >= 1; off >>= 1) {
    float mo = __shfl_xor(m, off, 64);
    float so = __shfl_xor(s, off, 64);
    merge_ms(m, s, mo, so);
  }
  __shared__ float ml[4], sl[4];
  if ((tid & 63) == 0) { ml[tid >> 6] = m; sl[tid >> 6] = s; }
  __syncthreads();
  if (tid == 0) {
#pragma unroll
    for (int w = 1; w < 4; w++) merge_ms(m, s, ml[w], sl[w]);
    ws[WS_M + e] = m;
    ws[WS_IS + e] = 1.f / s;
  }
}

// ---- t partials (normalized dispatch, R4 numerics):
// grid (8 col-blocks of 64 f4, 128 row-chunks of 64), block 256
__global__ __launch_bounds__(256) void k_tpart(const float* __restrict__ x,
                                               const float* __restrict__ rw,
                                               const float* __restrict__ ws,
                                               float* __restrict__ sc) {
  __shared__ f4 dv4[64][2];
  __shared__ f4 red[3][NE][64];
  int tid = threadIdx.x;
  int rc = blockIdx.y, b0 = rc * 64;
  if (tid < 128) {
    int row = tid >> 1, half = tid & 1;
    const float* rp = rw + (size_t)(b0 + row) * NE + half * 4;
    int e0 = half * 4;
    f4 d;
    d.x = __expf(rp[0] - ws[WS_M + e0 + 0]) * ws[WS_IS + e0 + 0];
    d.y = __expf(rp[1] - ws[WS_M + e0 + 1]) * ws[WS_IS + e0 + 1];
    d.z = __expf(rp[2] - ws[WS_M + e0 + 2]) * ws[WS_IS + e0 + 2];
    d.w = __expf(rp[3] - ws[WS_M + e0 + 3]) * ws[WS_IS + e0 + 3];
    dv4[row][half] = d;
  }
  __syncthreads();
  int col = tid & 63, rg = tid >> 6;
  int c4 = blockIdx.x * 64 + col;
  f4 acc[NE];
#pragma unroll
  for (int e = 0; e < NE; e++) acc[e] = (f4){0.f, 0.f, 0.f, 0.f};
  const f4* x4 = (const f4*)x;
#pragma unroll 4
  for (int r = 0; r < 16; r++) {
    int row = rg * 16 + r;
    f4 xv = __builtin_nontemporal_load(&x4[(size_t)(b0 + row) * 512 + c4]);
    f4 dlo = dv4[row][0], dhi = dv4[row][1];
    acc[0] += dlo.x * xv;
    acc[1] += dlo.y * xv;
    acc[2] += dlo.z * xv;
    acc[3] += dlo.w * xv;
    acc[4] += dhi.x * xv;
    acc[5] += dhi.y * xv;
    acc[6] += dhi.z * xv;
    acc[7] += dhi.w * xv;
  }
  if (rg) {
#pragma unroll
    for (int e = 0; e < NE; e++) red[rg - 1][e][col] = acc[e];
  }
  __syncthreads();
  if (!rg) {
    f4* o4 = (f4*)(sc + SC_TP);
#pragma unroll
    for (int e = 0; e < NE; e++) {
      f4 a = acc[e] + red[0][e][col] + red[1][e][col] + red[2][e][col];
      o4[(size_t)(rc * NE + e) * 512 + c4] = a;
    }
  }
}

// ---- t reduce: 512 blocks, 32 outputs each, 8 chunk-groups of 16 (double inner)
__global__ __launch_bounds__(256) void k_tred(const float* __restrict__ sc,
                                              float* __restrict__ ws) {
  __shared__ float red[8][32];
  int tid = threadIdx.x;
  int o = tid & 31, grp = tid >> 5;
  int i = blockIdx.x * 32 + o;
  double a = 0.0;
#pragma unroll 4
  for (int k = 0; k < 16; k++)
    a += (double)sc[SC_TP + (size_t)(grp * 16 + k) * (NE * HID) + i];
  red[grp][o] = (float)a;
  __syncthreads();
  if (tid < 32) {
    int ii = blockIdx.x * 32 + tid;
    float s = 0.f;
#pragma unroll
    for (int g = 0; g < 8; g++) s += red[g][tid];
    ws[WS_T + ii] = s;
  }
}

// ---- up-proj partials: grid (11 f-spans of 512, 16 h-chunks of 128, 4 groups)
__global__ __launch_bounds__(256) void k_midpart(const float* __restrict__ up_w,
                                                 const float* __restrict__ ws,
                                                 float* __restrict__ sc) {
  int fb = blockIdx.x, hc = blockIdx.y, g = blockIdx.z;
  int tid = threadIdx.x;
  __shared__ float t0[128], t1[128];
  int h0 = hc * 128;
  if (tid < 128) t0[tid] = ws[WS_T + (2 * g) * HID + h0 + tid];
  else t1[tid - 128] = ws[WS_T + (2 * g + 1) * HID + h0 + tid - 128];
  __syncthreads();
  int fA = fb * 512 + tid;  // < 5376 always
  int fB = fA + 256;
  bool hasB = fB < DFF;
  const float* wp = up_w + ((size_t)g * HID + h0) * DFF;
  float a0 = 0.f, a1 = 0.f, bb0 = 0.f, bb1 = 0.f;
#pragma unroll 8
  for (int h = 0; h < 128; h++) {
    float wA = __builtin_nontemporal_load(wp + (size_t)h * DFF + fA);
    float wB = hasB ? __builtin_nontemporal_load(wp + (size_t)h * DFF + fB) : 0.f;
    a0 += t0[h] * wA;
    a1 += t1[h] * wA;
    bb0 += t0[h] * wB;
    bb1 += t1[h] * wB;
  }
  float* mp = sc + SC_MP + (size_t)hc * NE * DFF;
  mp[(size_t)(2 * g) * DFF + fA] = a0;
  mp[(size_t)(2 * g + 1) * DFF + fA] = a1;
  if (hasB) {
    mp[(size_t)(2 * g) * DFF + fB] = bb0;
    mp[(size_t)(2 * g + 1) * DFF + fB] = bb1;
  }
}

// ---- down-proj: grid (2 h-halves, 127 f-chunks of 43, 8 experts), block 256
// fused mid reduce (double) + bias + silu, wave-local; 8-row preload pipeline
__global__ __launch_bounds__(256) void k_eopart(const float* __restrict__ down_w,
                                                const float* __restrict__ up_b,
                                                const float* __restrict__ sc_mp,
                                                float* __restrict__ sc) {
  int hb = blockIdx.x, fc = blockIdx.y, e = blockIdx.z;
  int tid = threadIdx.x;
  int f0 = fc * 43;
  const f4* base4 = (const f4*)down_w + ((size_t)e * DFF + f0) * 512 + hb * 256 + tid;
  // preload first 8 rows (in flight across the prologue)
  f4 w[8];
#pragma unroll
  for (int j = 0; j < 8; j++)
    w[j] = __builtin_nontemporal_load(&base4[(size_t)j * 512]);
  // wave-local mid finalize: 16-chunk reduce (double) + bias + silu
  __shared__ float ml[4][43];
  int lane = tid & 63, wv = tid >> 6;
  if (lane < 43) {
    double a = (double)up_b[(size_t)(e >> 1) * DFF + f0 + lane];
#pragma unroll 4
    for (int k = 0; k < 16; k++)
      a += (double)sc_mp[SC_MP + (size_t)(k * NE + e) * DFF + f0 + lane];
    float af = (float)a;
    ml[wv][lane] = af / (1.f + __expf(-af));
  }
  f4 acc = (f4){0.f, 0.f, 0.f, 0.f};
  for (int blk = 0; blk < 5; blk++) {
#pragma unroll
    for (int j = 0; j < 8; j++) {
      int cur = blk * 8 + j;
      f4 c = w[j];
      int nxt = cur + 8;
      if (nxt < 43) w[j] = __builtin_nontemporal_load(&base4[(size_t)nxt * 512]);
      acc += ml[wv][cur] * c;
    }
  }
#pragma unroll
  for (int j = 0; j < 3; j++) acc += ml[wv][40 + j] * w[j];
  ((f4*)(sc + SC_EP))[(size_t)(fc * NE + e) * 512 + hb * 256 + tid] = acc;
}

// ---- eo reduce + bias: 512 blocks, 32 outputs each (double inner)
__global__ __launch_bounds__(256) void k_eored(const float* __restrict__ sc,
                                               const float* __restrict__ down_b,
                                               float* __restrict__ ws) {
  __shared__ float red[8][32];
  int tid = threadIdx.x;
  int o = tid & 31, grp = tid >> 5;
  int i = blockIdx.x * 32 + o;
  double a = 0.0;
  for (int fc = grp; fc < 127; fc += 8)
    a += (double)sc[SC_EP + (size_t)fc * (NE * HID) + i];
  red[grp][o] = (float)a;
  __syncthreads();
  if (tid < 32) {
    int ii = blockIdx.x * 32 + tid;
    float s = down_b[ii];
#pragma unroll
    for (int g = 0; g < 8; g++) s += red[g][tid];
    ws[WS_EO + ii] = s;
  }
}

// ---- combine: 16 tokens/block, eo in regs, nt stores (R4 dispatch formula)
__global__ __launch_bounds__(256) void k_comb(const float* __restrict__ rw,
                                              const float* __restrict__ ws,
                                              float* __restrict__ y) {
  int tid = threadIdx.x;
  int b0 = blockIdx.x * 16;
  __shared__ float dvl[16][NE];
  if (tid < 128) {
    int tok = tid >> 3, e = tid & 7;
    dvl[tok][e] = __expf(rw[(size_t)(b0 + tok) * NE + e] - ws[WS_M + e]) *
                  ws[WS_IS + e];
  }
  __syncthreads();
  const f4* eo4 = (const f4*)(ws + WS_EO);
  f4 ea[NE], eb[NE];
#pragma unroll
  for (int e = 0; e < NE; e++) {
    ea[e] = eo4[e * 512 + tid];
    eb[e] = eo4[e * 512 + 256 + tid];
  }
  f4* y4 = (f4*)y;
#pragma unroll 4
  for (int t = 0; t < 16; t++) {
    f4 o0 = (f4){0.f, 0.f, 0.f, 0.f};
    f4 o1 = (f4){0.f, 0.f, 0.f, 0.f};
#pragma unroll
    for (int e = 0; e < NE; e++) {
      float d = dvl[t][e];
      o0 += d * ea[e];
      o1 += d * eb[e];
    }
    __builtin_nontemporal_store(o0, &y4[(size_t)(b0 + t) * 512 + tid]);
    __builtin_nontemporal_store(o1, &y4[(size_t)(b0 + t) * 512 + 256 + tid]);
  }
}

extern "C" void kernel_launch(void* const* d_in, const int* in_sizes, int n_in,
                              void* d_out, int out_size, void* d_ws, size_t ws_size,
                              hipStream_t stream) {
  const float* x      = (const float*)d_in[0];
  const float* rw     = (const float*)d_in[1];
  const float* up_w   = (const float*)d_in[2];
  const float* up_b   = (const float*)d_in[3];
  const float* down_w = (const float*)d_in[4];
  const float* down_b = (const float*)d_in[5];
  float* y  = (float*)d_out;
  float* ws = (float*)d_ws;
  float* sc = y;  // large scratch in d_out; k_comb overwrites all of it

  hipLaunchKernelGGL(k_stats, dim3(8), dim3(256), 0, stream, rw, ws);
  hipLaunchKernelGGL(k_tpart, dim3(8, 128), dim3(256), 0, stream, x, rw, ws, sc);
  hipLaunchKernelGGL(k_tred, dim3(512), dim3(256), 0, stream, sc, ws);
  hipLaunchKernelGGL(k_midpart, dim3(11, 16, 4), dim3(256), 0, stream, up_w, ws, sc);
  hipLaunchKernelGGL(k_eopart, dim3(2, 127, 8), dim3(256), 0, stream, down_w, up_b, sc, sc);
  hipLaunchKernelGGL(k_eored, dim3(512), dim3(256), 0, stream, sc, down_b, ws);
  hipLaunchKernelGGL(k_comb, dim3(512), dim3(256), 0, stream, rw, ws, y);
}

// Round 9
// 132.079 us; speedup vs baseline: 1.3908x; 1.0440x over previous
//
#include <hip/hip_runtime.h>

typedef float f4 __attribute__((ext_vector_type(4)));

#define HID 2048
#define DFF 5461
#define NE  8

// ws float offsets
#define WS_IS 0           // inv_s[8]
#define WS_T  64          // 8*2048 (normalized t)
#define WS_EO 16448       // 8*2048

// d_out used as large scratch (float offsets); fully overwritten by k_comb.
// Audited: SC_TP size 64*8*2048 = 1,048,576; SC_TS 512; SC_MP size 16*8*5461
// = 699,008 (end 1,748,608); SC_EP size 127*8*2048 = 2,080,768 (end 3,829,504).
#define SC_TP 0
#define SC_TS 1048576
#define SC_MP 1049600
#define SC_EP 1748736

// ---- t partials (unnormalized exp weights; s partials in double):
// grid (8 col-blocks of 64 f4, 64 row-chunks of 128), block 256
__global__ __launch_bounds__(256) void k_tpart(const float* __restrict__ x,
                                               const float* __restrict__ rw,
                                               float* __restrict__ sc) {
  __shared__ f4 dv4[64][2];
  __shared__ f4 red[3][NE][64];
  int tid = threadIdx.x;
  int rc = blockIdx.y;
  int col = tid & 63, rg = tid >> 6;
  int c4 = blockIdx.x * 64 + col;
  const f4* x4 = (const f4*)x;
  f4 acc[NE];
#pragma unroll
  for (int e = 0; e < NE; e++) acc[e] = (f4){0.f, 0.f, 0.f, 0.f};
  double spart = 0.0;
  for (int sub = 0; sub < 2; sub++) {
    int b0 = rc * 128 + sub * 64;
    if (tid < 128) {
      int row = tid >> 1, half = tid & 1;
      const float* rp = rw + (size_t)(b0 + row) * NE + half * 4;
      f4 d;
      d.x = __expf(rp[0]);
      d.y = __expf(rp[1]);
      d.z = __expf(rp[2]);
      d.w = __expf(rp[3]);
      dv4[row][half] = d;
    }
    __syncthreads();
    // exp-sum chunk partials (only col-block 0; threads 0..7) -- DOUBLE accum
    if (blockIdx.x == 0 && tid < NE) {
      const float* dp = (const float*)dv4;
      for (int row = 0; row < 64; row++) spart += (double)dp[row * 8 + tid];
    }
#pragma unroll 4
    for (int r = 0; r < 16; r++) {
      int row = rg * 16 + r;
      f4 xv = __builtin_nontemporal_load(&x4[(size_t)(b0 + row) * 512 + c4]);
      f4 dlo = dv4[row][0], dhi = dv4[row][1];
      acc[0] += dlo.x * xv;
      acc[1] += dlo.y * xv;
      acc[2] += dlo.z * xv;
      acc[3] += dlo.w * xv;
      acc[4] += dhi.x * xv;
      acc[5] += dhi.y * xv;
      acc[6] += dhi.z * xv;
      acc[7] += dhi.w * xv;
    }
    __syncthreads();
  }
  if (blockIdx.x == 0 && tid < NE) sc[SC_TS + rc * NE + tid] = (float)spart;
  if (rg) {
#pragma unroll
    for (int e = 0; e < NE; e++) red[rg - 1][e][col] = acc[e];
  }
  __syncthreads();
  if (!rg) {
    f4* o4 = (f4*)(sc + SC_TP);
#pragma unroll
    for (int e = 0; e < NE; e++) {
      f4 a = acc[e] + red[0][e][col] + red[1][e][col] + red[2][e][col];
      o4[(size_t)(rc * NE + e) * 512 + c4] = a;
    }
  }
}

// ---- t reduce + 1/s fold: 512 blocks, 32 outputs each, 8 chunk-groups of 8
__global__ __launch_bounds__(256) void k_tred(const float* __restrict__ sc,
                                              float* __restrict__ ws) {
  __shared__ float red[8][32];
  __shared__ float sinv[NE];
  int tid = threadIdx.x;
  if (tid < NE) {
    double s = 0.0;  // DOUBLE accum over 64 chunk partials
    for (int ch = 0; ch < 64; ch++) s += (double)sc[SC_TS + ch * NE + tid];
    float inv = (float)(1.0 / s);
    sinv[tid] = inv;
    if (blockIdx.x == 0) ws[WS_IS + tid] = inv;
  }
  int o = tid & 31, grp = tid >> 5;
  int i = blockIdx.x * 32 + o;
  double a = 0.0;
#pragma unroll 4
  for (int k = 0; k < 8; k++)
    a += (double)sc[SC_TP + (size_t)(grp * 8 + k) * (NE * HID) + i];
  red[grp][o] = (float)a;
  __syncthreads();
  if (tid < 32) {
    int ii = blockIdx.x * 32 + tid;
    float s = 0.f;
#pragma unroll
    for (int g = 0; g < 8; g++) s += red[g][tid];
    ws[WS_T + ii] = s * sinv[ii >> 11];
  }
}

// ---- up-proj partials: grid (11 f-spans of 512, 16 h-chunks of 128, 4 groups)
__global__ __launch_bounds__(256) void k_midpart(const float* __restrict__ up_w,
                                                 const float* __restrict__ ws,
                                                 float* __restrict__ sc) {
  int fb = blockIdx.x, hc = blockIdx.y, g = blockIdx.z;
  int tid = threadIdx.x;
  __shared__ float t0[128], t1[128];
  int h0 = hc * 128;
  if (tid < 128) t0[tid] = ws[WS_T + (2 * g) * HID + h0 + tid];
  else t1[tid - 128] = ws[WS_T + (2 * g + 1) * HID + h0 + tid - 128];
  __syncthreads();
  int fA = fb * 512 + tid;  // < 5376 always
  int fB = fA + 256;
  bool hasB = fB < DFF;
  const float* wp = up_w + ((size_t)g * HID + h0) * DFF;
  float a0 = 0.f, a1 = 0.f, bb0 = 0.f, bb1 = 0.f;
#pragma unroll 8
  for (int h = 0; h < 128; h++) {
    float wA = __builtin_nontemporal_load(wp + (size_t)h * DFF + fA);
    float wB = hasB ? __builtin_nontemporal_load(wp + (size_t)h * DFF + fB) : 0.f;
    a0 += t0[h] * wA;
    a1 += t1[h] * wA;
    bb0 += t0[h] * wB;
    bb1 += t1[h] * wB;
  }
  float* mp = sc + SC_MP + (size_t)hc * NE * DFF;
  mp[(size_t)(2 * g) * DFF + fA] = a0;
  mp[(size_t)(2 * g + 1) * DFF + fA] = a1;
  if (hasB) {
    mp[(size_t)(2 * g) * DFF + fB] = bb0;
    mp[(size_t)(2 * g + 1) * DFF + fB] = bb1;
  }
}

// ---- down-proj: grid (2 h-halves, 127 f-chunks of 43, 8 experts), block 256
// fused mid reduce (double) + bias + silu, wave-local; 8-row preload pipeline
__global__ __launch_bounds__(256) void k_eopart(const float* __restrict__ down_w,
                                                const float* __restrict__ up_b,
                                                const float* __restrict__ sc_mp,
                                                float* __restrict__ sc) {
  int hb = blockIdx.x, fc = blockIdx.y, e = blockIdx.z;
  int tid = threadIdx.x;
  int f0 = fc * 43;
  const f4* base4 = (const f4*)down_w + ((size_t)e * DFF + f0) * 512 + hb * 256 + tid;
  // preload first 8 rows (in flight across the prologue)
  f4 w[8];
#pragma unroll
  for (int j = 0; j < 8; j++)
    w[j] = __builtin_nontemporal_load(&base4[(size_t)j * 512]);
  // wave-local mid finalize: 16-chunk reduce (double) + bias + silu
  __shared__ float ml[4][43];
  int lane = tid & 63, wv = tid >> 6;
  if (lane < 43) {
    double a = (double)up_b[(size_t)(e >> 1) * DFF + f0 + lane];
#pragma unroll 4
    for (int k = 0; k < 16; k++)
      a += (double)sc_mp[SC_MP + (size_t)(k * NE + e) * DFF + f0 + lane];
    float af = (float)a;
    ml[wv][lane] = af / (1.f + __expf(-af));
  }
  f4 acc = (f4){0.f, 0.f, 0.f, 0.f};
  for (int blk = 0; blk < 5; blk++) {
#pragma unroll
    for (int j = 0; j < 8; j++) {
      int cur = blk * 8 + j;
      f4 c = w[j];
      int nxt = cur + 8;
      if (nxt < 43) w[j] = __builtin_nontemporal_load(&base4[(size_t)nxt * 512]);
      acc += ml[wv][cur] * c;
    }
  }
#pragma unroll
  for (int j = 0; j < 3; j++) acc += ml[wv][40 + j] * w[j];
  ((f4*)(sc + SC_EP))[(size_t)(fc * NE + e) * 512 + hb * 256 + tid] = acc;
}

// ---- eo reduce + bias: 512 blocks, 32 outputs each (double inner)
__global__ __launch_bounds__(256) void k_eored(const float* __restrict__ sc,
                                               const float* __restrict__ down_b,
                                               float* __restrict__ ws) {
  __shared__ float red[8][32];
  int tid = threadIdx.x;
  int o = tid & 31, grp = tid >> 5;
  int i = blockIdx.x * 32 + o;
  double a = 0.0;
  for (int fc = grp; fc < 127; fc += 8)
    a += (double)sc[SC_EP + (size_t)fc * (NE * HID) + i];
  red[grp][o] = (float)a;
  __syncthreads();
  if (tid < 32) {
    int ii = blockIdx.x * 32 + tid;
    float s = down_b[ii];
#pragma unroll
    for (int g = 0; g < 8; g++) s += red[g][tid];
    ws[WS_EO + ii] = s;
  }
}

// ---- combine: 16 tokens/block, eo in regs, nt stores
__global__ __launch_bounds__(256) void k_comb(const float* __restrict__ rw,
                                              const float* __restrict__ ws,
                                              float* __restrict__ y) {
  int tid = threadIdx.x;
  int b0 = blockIdx.x * 16;
  __shared__ float dvl[16][NE];
  if (tid < 128) {
    int tok = tid >> 3, e = tid & 7;
    dvl[tok][e] = __expf(rw[(size_t)(b0 + tok) * NE + e]) * ws[WS_IS + e];
  }
  __syncthreads();
  const f4* eo4 = (const f4*)(ws + WS_EO);
  f4 ea[NE], eb[NE];
#pragma unroll
  for (int e = 0; e < NE; e++) {
    ea[e] = eo4[e * 512 + tid];
    eb[e] = eo4[e * 512 + 256 + tid];
  }
  f4* y4 = (f4*)y;
#pragma unroll 4
  for (int t = 0; t < 16; t++) {
    f4 o0 = (f4){0.f, 0.f, 0.f, 0.f};
    f4 o1 = (f4){0.f, 0.f, 0.f, 0.f};
#pragma unroll
    for (int e = 0; e < NE; e++) {
      float d = dvl[t][e];
      o0 += d * ea[e];
      o1 += d * eb[e];
    }
    __builtin_nontemporal_store(o0, &y4[(size_t)(b0 + t) * 512 + tid]);
    __builtin_nontemporal_store(o1, &y4[(size_t)(b0 + t) * 512 + 256 + tid]);
  }
}

extern "C" void kernel_launch(void* const* d_in, const int* in_sizes, int n_in,
                              void* d_out, int out_size, void* d_ws, size_t ws_size,
                              hipStream_t stream) {
  const float* x      = (const float*)d_in[0];
  const float* rw     = (const float*)d_in[1];
  const float* up_w   = (const float*)d_in[2];
  const float* up_b   = (const float*)d_in[3];
  const float* down_w = (const float*)d_in[4];
  const float* down_b = (const float*)d_in[5];
  float* y  = (float*)d_out;
  float* ws = (float*)d_ws;
  float* sc = y;  // large scratch in d_out; k_comb overwrites all of it

  hipLaunchKernelGGL(k_tpart, dim3(8, 64), dim3(256), 0, stream, x, rw, sc);
  hipLaunchKernelGGL(k_tred, dim3(512), dim3(256), 0, stream, sc, ws);
  hipLaunchKernelGGL(k_midpart, dim3(11, 16, 4), dim3(256), 0, stream, up_w, ws, sc);
  hipLaunchKernelGGL(k_eopart, dim3(2, 127, 8), dim3(256), 0, stream, down_w, up_b, sc, sc);
  hipLaunchKernelGGL(k_eored, dim3(512), dim3(256), 0, stream, sc, down_b, ws);
  hipLaunchKernelGGL(k_comb, dim3(512), dim3(256), 0, stream, rw, ws, y);
}